// Round 10
// baseline (343.764 us; speedup 1.0000x reference)
//
#include <hip/hip_runtime.h>

#define GXc 96
#define GYc 96
#define RFc 24
#define Bc 8
#define Nc (GXc * GYc)          // 9216
#define Hc (GXc - 1 + RFc)      // 119
#define IN_IMG (Hc * Hc)        // 14161
#define RF2 (RFc * RFc)         // 576
#define GAMMA 0.9f

// ---------------- Kernel A: afferent with LDS input tiling -----------------
#define A_GJW 16                              // gj chunk per block
#define A_COLS (A_GJW - 1 + RFc)              // 39
#define A_PAD 40
#define A_NBLK (GXc * (GYc / A_GJW))          // 576

__global__ __launch_bounds__(256) void afferent_kernel(
    const float* __restrict__ input,   // (B, 119, 119)
    const float* __restrict__ aw,      // (N, 576)
    float* __restrict__ aff)           // (B, N) scratch
{
    __shared__ float li[Bc][RFc][A_PAD];      // 30.7 KB

    const int tid  = threadIdx.x;
    const int wave = tid >> 6;
    const int lane = tid & 63;
    const int gi   = blockIdx.x / (GYc / A_GJW);
    const int gj0  = (blockIdx.x % (GYc / A_GJW)) * A_GJW;

    for (int i = tid; i < Bc * RFc * A_COLS; i += 256) {
        const int b = i / (RFc * A_COLS);
        const int rem = i - b * (RFc * A_COLS);
        const int h = rem / A_COLS;
        const int c = rem - h * A_COLS;
        li[b][h][c] = input[b * IN_IMG + (gi + h) * Hc + gj0 + c];
    }
    __syncthreads();

#pragma unroll
    for (int q = 0; q < 4; ++q) {
        const int cc = wave * 4 + q;          // 0..15
        const int n  = gi * GYc + gj0 + cc;
        const float* awn = aw + (size_t)n * RF2;
        float acc[Bc];
#pragma unroll
        for (int b = 0; b < Bc; ++b) acc[b] = 0.f;
#pragma unroll
        for (int t = 0; t < RF2 / 64; ++t) {  // 9 iters
            const int hw = t * 64 + lane;
            const int h  = hw / RFc;
            const int w  = hw - h * RFc;
            const float av = awn[hw];
#pragma unroll
            for (int b = 0; b < Bc; ++b)
                acc[b] += li[b][h][cc + w] * av;
        }
#pragma unroll
        for (int b = 0; b < Bc; ++b) {
            float v = acc[b];
            v += __shfl_xor(v, 1);
            v += __shfl_xor(v, 2);
            v += __shfl_xor(v, 4);
            v += __shfl_xor(v, 8);
            v += __shfl_xor(v, 16);
            v += __shfl_xor(v, 32);
            if (lane == b) aff[b * Nc + n] = v;
        }
    }
}

// ---------------- Kernel B: barrier-free lateral quarter stream ------------
// Block = (k-quarter q, 72-row chunk). Stage prev quarter (73.7 KB) in LDS
// ONCE; each wave then privately streams 9 rows x quarter of We/Wi with a
// depth-3 register ring (W prefetch lead = 2 sweeps) and NO barriers.
#define QK (Nc / 4)             // 2304 floats per quarter
#define NSWEEP (QK / 256)       // 9 sweeps per row-quarter
#define RPW 9                   // rows per wave
#define LWAVES 8                // waves per block (512 threads)
#define RPB (RPW * LWAVES)      // 72 rows per block
#define LBLOCKS (4 * (Nc / RPB))// 4 quarters x 128 = 512 = exactly 2 blocks/CU

__device__ __forceinline__ float dot4f(float4 a, float4 b) {
    return a.x * b.x + a.y * b.y + a.z * b.z + a.w * b.w;
}

// Step S: issue sweep S+2 of the W ring into slot (S+2)%3, then consume
// slot S%3 against the LDS p-sweep. Compiler's auto-wait for the consumed
// slot is vmcnt(4) (the two newer sweep-pairs stay in flight).
#define LSTEP(S, CE, CI, TE, TI)                                              \
  {                                                                           \
    if ((S) + 2 < NSWEEP) {                                                   \
      TE = *(const float4*)(we_row + ((S) + 2) * 256 + koff);                 \
      TI = *(const float4*)(wi_row + ((S) + 2) * 256 + koff);                 \
    } else {                                                                  \
      TE = *(const float4*)(we_nxt + ((S) + 2 - NSWEEP) * 256 + koff);        \
      TI = *(const float4*)(wi_nxt + ((S) + 2 - NSWEEP) * 256 + koff);        \
    }                                                                         \
    const float4 wd = make_float4(CE.x - CI.x, CE.y - CI.y,                   \
                                  CE.z - CI.z, CE.w - CI.w);                  \
    _Pragma("unroll")                                                         \
    for (int b = 0; b < Bc; ++b) {                                            \
      const float4 p4 = *(const float4*)&pq[b][(S) * 256 + (lane << 2)];      \
      acc[b] += dot4f(wd, p4);                                                \
    }                                                                         \
  }

__global__ __launch_bounds__(512) void lateral_kernel(
    const float* __restrict__ prev,    // (B, N)
    const float* __restrict__ We,      // (N, N)
    const float* __restrict__ Wi,      // (N, N)
    float* __restrict__ partial)       // (4, B, N) scratch
{
    __shared__ float pq[Bc][QK];       // 73.7 KB -> 2 blocks/CU

    const int tid   = threadIdx.x;
    const int wave  = tid >> 6;
    const int lane  = tid & 63;
    const int q     = blockIdx.x & 3;
    const int chunk = blockIdx.x >> 2;
    const int koff  = lane << 2;

    // ---- stage prev quarter into LDS (the kernel's ONLY barrier) ----------
    for (int i = tid; i < Bc * (QK / 4); i += 512) {        // 9 iters exact
        const int b  = i / (QK / 4);
        const int k4 = i - b * (QK / 4);
        *(float4*)&pq[b][k4 * 4] =
            *(const float4*)(prev + b * Nc + q * QK + k4 * 4);
    }
    __syncthreads();

    float* pout = partial + (size_t)q * Bc * Nc;

    int n = chunk * RPB + wave * RPW;
    const float* we_row = We + (size_t)n * Nc + q * QK;
    const float* wi_row = Wi + (size_t)n * Nc + q * QK;

    // ring prologue: sweeps 0,1 of row 0
    float4 eA = *(const float4*)(we_row + 0 * 256 + koff);
    float4 iA = *(const float4*)(wi_row + 0 * 256 + koff);
    float4 eB = *(const float4*)(we_row + 1 * 256 + koff);
    float4 iB = *(const float4*)(wi_row + 1 * 256 + koff);
    float4 eC, iC;

    for (int i = 0; i < RPW; ++i, ++n) {
        const float* we_nxt = (n + 1 < Nc) ? we_row + Nc : we_row;  // clamp
        const float* wi_nxt = (n + 1 < Nc) ? wi_row + Nc : wi_row;

        float acc[Bc];
#pragma unroll
        for (int b = 0; b < Bc; ++b) acc[b] = 0.f;

        LSTEP(0, eA, iA, eC, iC)
        LSTEP(1, eB, iB, eA, iA)
        LSTEP(2, eC, iC, eB, iB)
        LSTEP(3, eA, iA, eC, iC)
        LSTEP(4, eB, iB, eA, iA)
        LSTEP(5, eC, iC, eB, iB)
        LSTEP(6, eA, iA, eC, iC)
        LSTEP(7, eB, iB, eA, iA)   // issues next row sweep 0 -> slot A
        LSTEP(8, eC, iC, eB, iB)   // issues next row sweep 1 -> slot B

        // per-row butterfly reduce + one store per batch
#pragma unroll
        for (int b = 0; b < Bc; ++b) {
            float v = acc[b];
            v += __shfl_xor(v, 1);
            v += __shfl_xor(v, 2);
            v += __shfl_xor(v, 4);
            v += __shfl_xor(v, 8);
            v += __shfl_xor(v, 16);
            v += __shfl_xor(v, 32);
            if (lane == b) pout[b * Nc + n] = v;
        }

        we_row = we_nxt;
        wi_row = wi_nxt;
    }
}

// ---------------- Kernel C: combine partials + afferent + relu -------------
__global__ __launch_bounds__(256) void combine_kernel(
    const float* __restrict__ partial, // (4, B, N)
    const float* __restrict__ aff,     // (B, N)
    float* __restrict__ out)           // (B, N)
{
    const int idx = (blockIdx.x * 256 + threadIdx.x) * 4;   // 72 blocks exact
    const float4 a  = *(const float4*)(aff + idx);
    const float4 p0 = *(const float4*)(partial + 0 * Bc * Nc + idx);
    const float4 p1 = *(const float4*)(partial + 1 * Bc * Nc + idx);
    const float4 p2 = *(const float4*)(partial + 2 * Bc * Nc + idx);
    const float4 p3 = *(const float4*)(partial + 3 * Bc * Nc + idx);
    float4 r;
    r.x = a.x + GAMMA * (p0.x + p1.x + p2.x + p3.x);
    r.y = a.y + GAMMA * (p0.y + p1.y + p2.y + p3.y);
    r.z = a.z + GAMMA * (p0.z + p1.z + p2.z + p3.z);
    r.w = a.w + GAMMA * (p0.w + p1.w + p2.w + p3.w);
    r.x = r.x > 0.f ? r.x : 0.f;
    r.y = r.y > 0.f ? r.y : 0.f;
    r.z = r.z > 0.f ? r.z : 0.f;
    r.w = r.w > 0.f ? r.w : 0.f;
    *(float4*)(out + idx) = r;
}

extern "C" void kernel_launch(void* const* d_in, const int* in_sizes, int n_in,
                              void* d_out, int out_size, void* d_ws, size_t ws_size,
                              hipStream_t stream) {
    const float* input = (const float*)d_in[0];
    const float* prev  = (const float*)d_in[1];
    const float* aw    = (const float*)d_in[2];
    const float* We    = (const float*)d_in[3];
    const float* Wi    = (const float*)d_in[4];
    float* out = (float*)d_out;

    float* aff     = (float*)d_ws;                 // 73728 floats
    float* partial = aff + Bc * Nc;                // 4 x 73728 floats (1.47 MB total)

    afferent_kernel<<<A_NBLK, 256, 0, stream>>>(input, aw, aff);
    lateral_kernel<<<LBLOCKS, 512, 0, stream>>>(prev, We, Wi, partial);
    combine_kernel<<<(Bc * Nc) / (256 * 4), 256, 0, stream>>>(partial, aff, out);
}

// Round 11
// 138.843 us; speedup vs baseline: 2.4759x; 2.4759x over previous
//
#include <hip/hip_runtime.h>

#define GXc 96
#define GYc 96
#define RFc 24
#define Bc 8
#define Nc (GXc * GYc)          // 9216
#define Hc (GXc - 1 + RFc)      // 119
#define IN_IMG (Hc * Hc)        // 14161
#define RF2 (RFc * RFc)         // 576
#define GAMMA 0.9f
#define INV_GAMMA (1.0f / 0.9f)

#define ROWS 3                  // output rows per wave
#define WAVES_PER_BLOCK 4
#define ROWS_PER_BLOCK (ROWS * WAVES_PER_BLOCK)   // 12
#define NBLOCKS (Nc / ROWS_PER_BLOCK)             // 768 = exactly 3 blocks/CU
#define KW 256                                    // k-window (floats)
#define KITERS (Nc / KW)                          // 36

__global__ __launch_bounds__(256) void cortex_fused_kernel(
    const float* __restrict__ input,   // (B, 119, 119)
    const float* __restrict__ prev,    // (B, N)
    const float* __restrict__ aw,      // (N, 576)
    const float* __restrict__ We,      // (N, N)
    const float* __restrict__ Wi,      // (N, N)
    float* __restrict__ out)           // (B, N)
{
    __shared__ float pv[2][Bc][KW];    // double-buffered prev k-window, 16 KB

    const int tid  = threadIdx.x;
    const int wave = tid >> 6;
    const int lane = tid & 63;
    const int rowbase = blockIdx.x * ROWS_PER_BLOCK + wave * ROWS;
    const int koff = lane << 2;        // float4 slot within window
    const int b0 = wave * 2;           // each wave stages 2 batches of the window
    const int b1 = wave * 2 + 1;

    float acc[ROWS][Bc];
#pragma unroll
    for (int r = 0; r < ROWS; ++r)
#pragma unroll
        for (int b = 0; b < Bc; ++b) acc[r][b] = 0.f;

    // ---------------- afferent (local RF conv), all-lane k layout ----------
#pragma unroll
    for (int r = 0; r < ROWS; ++r) {
        const int n  = rowbase + r;
        const int gi = n / GYc;
        const int gj = n - gi * GYc;
        const float* awn = aw + (size_t)n * RF2;
        const int base = gi * Hc + gj;
#pragma unroll
        for (int t = 0; t < RF2 / 64; ++t) {   // 9 iters
            const int hw = t * 64 + lane;
            const int h  = hw / RFc;
            const int w  = hw - h * RFc;
            const float av  = awn[hw] * INV_GAMMA;
            const int  off  = base + h * Hc + w;
#pragma unroll
            for (int b = 0; b < Bc; ++b)
                acc[r][b] += input[b * IN_IMG + off] * av;
        }
    }

    // ---------------- lateral: prev @ (We - Wi)^T, software-pipelined ------
    // Prologue: stage window 0 into LDS buf 0, W rows window 0 into regs.
    float4 t0 = *(const float4*)(prev + b0 * Nc + koff);
    float4 t1 = *(const float4*)(prev + b1 * Nc + koff);
    float4 weC[ROWS], wiC[ROWS];
#pragma unroll
    for (int r = 0; r < ROWS; ++r) {
        const size_t ro = (size_t)(rowbase + r) * Nc + koff;
        weC[r] = *(const float4*)(We + ro);
        wiC[r] = *(const float4*)(Wi + ro);
    }
    *(float4*)&pv[0][b0][koff] = t0;
    *(float4*)&pv[0][b1][koff] = t1;
    __syncthreads();

    int cur = 0;
    for (int j = 0; j < KITERS - 1; ++j) {
        const int k1 = (j + 1) * KW + koff;

        // issue next-window loads first (latency hidden under compute below)
        const float4 nt0 = *(const float4*)(prev + b0 * Nc + k1);
        const float4 nt1 = *(const float4*)(prev + b1 * Nc + k1);
        float4 weN[ROWS], wiN[ROWS];
#pragma unroll
        for (int r = 0; r < ROWS; ++r) {
            const size_t ro = (size_t)(rowbase + r) * Nc + k1;
            weN[r] = *(const float4*)(We + ro);
            wiN[r] = *(const float4*)(Wi + ro);
        }

        // compute current window from LDS + current W regs
        float4 wd[ROWS];
#pragma unroll
        for (int r = 0; r < ROWS; ++r)
            wd[r] = make_float4(weC[r].x - wiC[r].x, weC[r].y - wiC[r].y,
                                weC[r].z - wiC[r].z, weC[r].w - wiC[r].w);
#pragma unroll
        for (int b = 0; b < Bc; ++b) {
            const float4 p = *(const float4*)&pv[cur][b][koff];
#pragma unroll
            for (int r = 0; r < ROWS; ++r)
                acc[r][b] += wd[r].x * p.x + wd[r].y * p.y
                           + wd[r].z * p.z + wd[r].w * p.w;
        }

        // stage next window into the other LDS buffer; rotate W regs
        *(float4*)&pv[cur ^ 1][b0][koff] = nt0;
        *(float4*)&pv[cur ^ 1][b1][koff] = nt1;
#pragma unroll
        for (int r = 0; r < ROWS; ++r) { weC[r] = weN[r]; wiC[r] = wiN[r]; }
        __syncthreads();
        cur ^= 1;
    }

    // final (peeled) window
    {
        float4 wd[ROWS];
#pragma unroll
        for (int r = 0; r < ROWS; ++r)
            wd[r] = make_float4(weC[r].x - wiC[r].x, weC[r].y - wiC[r].y,
                                weC[r].z - wiC[r].z, weC[r].w - wiC[r].w);
#pragma unroll
        for (int b = 0; b < Bc; ++b) {
            const float4 p = *(const float4*)&pv[cur][b][koff];
#pragma unroll
            for (int r = 0; r < ROWS; ++r)
                acc[r][b] += wd[r].x * p.x + wd[r].y * p.y
                           + wd[r].z * p.z + wd[r].w * p.w;
        }
    }

    // ---------------- butterfly reduce + static-index epilogue -------------
#pragma unroll
    for (int r = 0; r < ROWS; ++r)
#pragma unroll
        for (int b = 0; b < Bc; ++b) {
            float v = acc[r][b];
            v += __shfl_xor(v, 1);
            v += __shfl_xor(v, 2);
            v += __shfl_xor(v, 4);
            v += __shfl_xor(v, 8);
            v += __shfl_xor(v, 16);
            v += __shfl_xor(v, 32);
            if (lane == b * ROWS + r) {          // compile-time (r,b): lane 0..23
                const float tot = GAMMA * v;
                out[b * Nc + rowbase + r] = tot > 0.f ? tot : 0.f;
            }
        }
}

extern "C" void kernel_launch(void* const* d_in, const int* in_sizes, int n_in,
                              void* d_out, int out_size, void* d_ws, size_t ws_size,
                              hipStream_t stream) {
    const float* input = (const float*)d_in[0];
    const float* prev  = (const float*)d_in[1];
    const float* aw    = (const float*)d_in[2];
    const float* We    = (const float*)d_in[3];
    const float* Wi    = (const float*)d_in[4];
    // d_in[5], d_in[6] are rf_x / rf_y == arange(96): identity, folded into indexing.
    float* out = (float*)d_out;

    cortex_fused_kernel<<<NBLOCKS, 256, 0, stream>>>(input, prev, aw, We, Wi, out);
}